// Round 10
// baseline (772.795 us; speedup 1.0000x reference)
//
#include <hip/hip_runtime.h>
#include <math.h>

typedef __attribute__((ext_vector_type(8))) short bf16x8;
typedef __attribute__((ext_vector_type(4))) float f32x4;
typedef __attribute__((ext_vector_type(4))) _Float16 f16x4;
typedef __attribute__((ext_vector_type(8))) _Float16 f16x8;

__device__ __forceinline__ unsigned short f2bf(float f) {
    unsigned int u = __float_as_uint(f);
    unsigned int r = (u + 0x7FFF + ((u >> 16) & 1)) >> 16;  // RNE
    return (unsigned short)r;
}
__device__ __forceinline__ float bf2f(unsigned short h) {
    return __uint_as_float((unsigned int)h << 16);
}
__device__ __forceinline__ void split_bf(float x, unsigned short& hi, unsigned short& lo) {
    hi = f2bf(x);
    lo = f2bf(x - bf2f(hi));
}

// ---------------- CSR build ----------------

__global__ void k_hist(const int* __restrict__ dst, int* __restrict__ deg, int e) {
    int t = blockIdx.x * 256 + threadIdx.x;
    if (t < e) atomicAdd(&deg[dst[t]], 1);
}

__global__ void k_scan1(const int* __restrict__ deg, int* __restrict__ tmp,
                        int* __restrict__ bsum, int n) {
    __shared__ int s[1024];
    int t = threadIdx.x;
    int g = blockIdx.x * 1024 + t;
    int v = (g < n) ? deg[g] : 0;
    s[t] = v;
    __syncthreads();
    for (int off = 1; off < 1024; off <<= 1) {
        int u = (t >= off) ? s[t - off] : 0;
        __syncthreads();
        s[t] += u;
        __syncthreads();
    }
    if (g < n) tmp[g] = s[t];
    if (t == 1023) bsum[blockIdx.x] = s[t];
}

__global__ void k_scan2(int* bsum, int nb) {
    int acc = 0;
    for (int b = 0; b < nb; ++b) { int v = bsum[b]; bsum[b] = acc; acc += v; }
}

__global__ void k_scan3(const int* __restrict__ deg, const int* __restrict__ tmp,
                        const int* __restrict__ bsum, int* __restrict__ rowptr,
                        int* __restrict__ cursor, int n) {
    int g = blockIdx.x * 256 + threadIdx.x;
    if (g < n) {
        int incl = tmp[g] + bsum[g >> 10];
        rowptr[g + 1] = incl;
        cursor[g] = incl - deg[g];
        if (g == 0) rowptr[0] = 0;
    }
}

__global__ void k_scatter(const int* __restrict__ src, const int* __restrict__ dst,
                          int* __restrict__ cursor, int* __restrict__ csr, int e) {
    int t = blockIdx.x * 256 + threadIdx.x;
    if (t < e) {
        int d = dst[t];
        int pos = atomicAdd(&cursor[d], 1);
        csr[pos] = src[t];
    }
}

// ---------------- casts (split hi/lo) ----------------

__global__ void k_castx(const float* __restrict__ x, unsigned short* __restrict__ xhi,
                        unsigned short* __restrict__ xlo, int nelem) {
    int t = blockIdx.x * 256 + threadIdx.x;
    if (t < nelem) {
        unsigned short h, l;
        split_bf(x[t], h, l);
        xhi[t] = h; xlo[t] = l;
    }
}

__global__ void k_castw(const float* __restrict__ W, unsigned short* __restrict__ Whi,
                        unsigned short* __restrict__ Wlo, int K, int N) {
    int t = blockIdx.x * 256 + threadIdx.x;
    if (t < K * N) {
        int k = t / N, n = t - k * N;
        unsigned short h, l;
        split_bf(W[t], h, l);
        Whi[n * K + k] = h; Wlo[n * K + k] = l;
    }
}

// ------- split-bf16 MFMA GEMM (NT): C = A @ Bt^T, ~fp32 accuracy ----------

#define LDP 40

__global__ __launch_bounds__(256) void k_gemm_split(const unsigned short* __restrict__ Ahi,
                                                    const unsigned short* __restrict__ Alo,
                                                    const unsigned short* __restrict__ Bhi,
                                                    const unsigned short* __restrict__ Blo,
                                                    _Float16* __restrict__ C,
                                                    int M, int Ncol, int K) {
    __shared__ unsigned short Ash[64 * LDP];
    __shared__ unsigned short Asl[64 * LDP];
    __shared__ unsigned short Bsh[64 * LDP];
    __shared__ unsigned short Bsl[64 * LDP];
    int t = threadIdx.x;
    int w = t >> 6, lane = t & 63;
    int lrow = lane & 15, kgrp = (lane >> 4) * 8;
    int row0 = blockIdx.x * 64, col0 = blockIdx.y * 64;
    int trow = t >> 2, tcol = (t & 3) * 8;

    f32x4 acc[4] = {{0.f, 0.f, 0.f, 0.f}, {0.f, 0.f, 0.f, 0.f},
                    {0.f, 0.f, 0.f, 0.f}, {0.f, 0.f, 0.f, 0.f}};

    for (int k0 = 0; k0 < K; k0 += 32) {
        uint4 ah = {0u,0u,0u,0u}, al = {0u,0u,0u,0u};
        uint4 bh = {0u,0u,0u,0u}, bl = {0u,0u,0u,0u};
        int gr = row0 + trow;
        if (gr < M) {
            ah = *(const uint4*)(Ahi + (size_t)gr * K + k0 + tcol);
            al = *(const uint4*)(Alo + (size_t)gr * K + k0 + tcol);
        }
        int gc = col0 + trow;
        if (gc < Ncol) {
            bh = *(const uint4*)(Bhi + (size_t)gc * K + k0 + tcol);
            bl = *(const uint4*)(Blo + (size_t)gc * K + k0 + tcol);
        }
        __syncthreads();
        *(uint4*)&Ash[trow * LDP + tcol] = ah;
        *(uint4*)&Asl[trow * LDP + tcol] = al;
        *(uint4*)&Bsh[trow * LDP + tcol] = bh;
        *(uint4*)&Bsl[trow * LDP + tcol] = bl;
        __syncthreads();
        bf16x8 vbh = *(const bf16x8*)&Bsh[(w * 16 + lrow) * LDP + kgrp];
        bf16x8 vbl = *(const bf16x8*)&Bsl[(w * 16 + lrow) * LDP + kgrp];
        #pragma unroll
        for (int mt = 0; mt < 4; ++mt) {
            bf16x8 vah = *(const bf16x8*)&Ash[(mt * 16 + lrow) * LDP + kgrp];
            bf16x8 val = *(const bf16x8*)&Asl[(mt * 16 + lrow) * LDP + kgrp];
            acc[mt] = __builtin_amdgcn_mfma_f32_16x16x32_bf16(vah, vbh, acc[mt], 0, 0, 0);
            acc[mt] = __builtin_amdgcn_mfma_f32_16x16x32_bf16(val, vbh, acc[mt], 0, 0, 0);
            acc[mt] = __builtin_amdgcn_mfma_f32_16x16x32_bf16(vah, vbl, acc[mt], 0, 0, 0);
        }
    }

    int ocol = col0 + w * 16 + lrow;
    if (ocol < Ncol) {
        int orow = (lane >> 4) * 4;
        #pragma unroll
        for (int mt = 0; mt < 4; ++mt) {
            #pragma unroll
            for (int r = 0; r < 4; ++r) {
                int m = row0 + mt * 16 + orow + r;
                if (m < M) C[(size_t)m * Ncol + ocol] = (_Float16)acc[mt][r];
            }
        }
    }
}

static inline void gemm_split(const unsigned short* Ah, const unsigned short* Al,
                              const unsigned short* Bh, const unsigned short* Bl,
                              _Float16* C, int M, int Ncol, int K, hipStream_t st) {
    dim3 g((M + 63) / 64, (Ncol + 63) / 64);
    k_gemm_split<<<g, 256, 0, st>>>(Ah, Al, Bh, Bl, C, M, Ncol, K);
}

// ---------------- attention scores ----------------

// H=1 layers (feat [n, D])
template <int H, int D>
__global__ __launch_bounds__(256) void k_attn(const _Float16* __restrict__ feat,
                                              const float* __restrict__ al,
                                              const float* __restrict__ ar,
                                              float* __restrict__ el,
                                              float* __restrict__ er, int n) {
    int gw = blockIdx.x * 4 + (threadIdx.x >> 6);
    int lane = threadIdx.x & 63;
    int i = gw / H, h = gw % H;
    if (i >= n) return;
    float f = (lane < D) ? (float)feat[i * (H * D) + h * D + lane] : 0.f;
    float wl = (lane < D) ? al[h * D + lane] : 0.f;
    float wr = (lane < D) ? ar[h * D + lane] : 0.f;
    float pl = f * wl, pr = f * wr;
    #pragma unroll
    for (int off = 32; off; off >>= 1) {
        pl += __shfl_xor(pl, off);
        pr += __shfl_xor(pr, off);
    }
    if (lane == 0) {
        el[i * H + h] = pl;
        er[i * H + h] = pr;
    }
}

// fused layer-1: 8 heads over feat01 [n, 512]; heads 0-3 branch0 (a0), 4-7 branch1 (a1)
__global__ __launch_bounds__(256) void k_attn8(const _Float16* __restrict__ feat,
                                               const float* __restrict__ a0l,
                                               const float* __restrict__ a0r,
                                               const float* __restrict__ a1l,
                                               const float* __restrict__ a1r,
                                               float* __restrict__ el,
                                               float* __restrict__ er, int n) {
    int gw = blockIdx.x * 4 + (threadIdx.x >> 6);
    int lane = threadIdx.x & 63;
    int i = gw >> 3, h = gw & 7;
    if (i >= n) return;
    const float* wl = (h < 4) ? (a0l + h * 64) : (a1l + (h - 4) * 64);
    const float* wr = (h < 4) ? (a0r + h * 64) : (a1r + (h - 4) * 64);
    float f = (float)feat[(size_t)i * 512 + h * 64 + lane];
    float pl = f * wl[lane], pr = f * wr[lane];
    #pragma unroll
    for (int off = 32; off; off >>= 1) {
        pl += __shfl_xor(pl, off);
        pr += __shfl_xor(pr, off);
    }
    if (lane == 0) {
        el[i * 8 + h] = pl;
        er[i * 8 + h] = pr;
    }
}

__device__ __forceinline__ float lrelu(float v) { return v > 0.f ? v : 0.2f * v; }

// ---------------- fused layer-1 aggregation: 8 heads, one wave/node --------
// Lane owns 8 contiguous channels of feat01 [n,512]: one f16x8 (16B) load
// covers the whole 512-ch src row in ONE 1KB wave transaction per edge.
// exp stage: lane=(eidx 0..7, h 0..7) over 8-edge tiles; per-head butterfly
// over offsets {8,16,32}. Both branch halves get ELU. Output split-bf16 to
// separate branch buffers (lanes 0-31 -> branch0, 32-63 -> branch1).
__global__ __launch_bounds__(256) void k_agg8(const int* __restrict__ rowptr,
                                              const int* __restrict__ csr,
                                              const float* __restrict__ el,
                                              const float* __restrict__ er,
                                              const _Float16* __restrict__ feat,
                                              unsigned short* __restrict__ o0hi,
                                              unsigned short* __restrict__ o0lo,
                                              unsigned short* __restrict__ o1hi,
                                              unsigned short* __restrict__ o1lo, int n) {
    __shared__ int   s_src[4][8];
    __shared__ float s_ex[4][64];
    __shared__ float s_den[4][8];
    int w = threadIdx.x >> 6;
    int lane = threadIdx.x & 63;
    int i = blockIdx.x * 4 + w;
    if (i >= n) return;
    int s0 = rowptr[i], s1 = rowptr[i + 1];
    int deg = s1 - s0;
    int eidx = lane >> 3, h = lane & 7;  // exp-stage role
    int hh = lane >> 3;                  // FMA-stage head (ch = lane*8 -> head = lane/8)
    float erh = er[i * 8 + h];

    float den = 0.f;
    float a[8] = {0.f, 0.f, 0.f, 0.f, 0.f, 0.f, 0.f, 0.f};

    auto fma_chunk = [&](int cnt) {
        int j = 0;
        for (; j + 2 <= cnt; j += 2) {
            int sj0 = s_src[w][j], sj1 = s_src[w][j + 1];
            float x0 = s_ex[w][j * 8 + hh], x1 = s_ex[w][(j + 1) * 8 + hh];
            f16x8 f0 = *(const f16x8*)&feat[(size_t)sj0 * 512 + (lane << 3)];
            f16x8 f1 = *(const f16x8*)&feat[(size_t)sj1 * 512 + (lane << 3)];
            #pragma unroll
            for (int q = 0; q < 8; ++q)
                a[q] = fmaf(x0, (float)f0[q], fmaf(x1, (float)f1[q], a[q]));
        }
        for (; j < cnt; ++j) {
            int sj = s_src[w][j];
            float x = s_ex[w][j * 8 + hh];
            f16x8 f0 = *(const f16x8*)&feat[(size_t)sj * 512 + (lane << 3)];
            #pragma unroll
            for (int q = 0; q < 8; ++q)
                a[q] = fmaf(x, (float)f0[q], a[q]);
        }
    };

    if (deg <= 8) {
        int e = s0 + eidx;
        int s = 0;
        float v = -INFINITY;
        if (e < s1) {
            s = csr[e];
            v = lrelu(el[s * 8 + h] + erh);
        }
        float m = v;
        #pragma unroll
        for (int off = 8; off < 64; off <<= 1) m = fmaxf(m, __shfl_xor(m, off));
        float ex = (e < s1) ? __expf(v - m) : 0.f;
        den = ex;
        if (h == 0) s_src[w][eidx] = s;
        s_ex[w][lane] = ex;
        fma_chunk(deg);
    } else {
        float m = -INFINITY;
        for (int e = s0 + eidx; e < s1; e += 8)
            m = fmaxf(m, lrelu(el[csr[e] * 8 + h] + erh));
        #pragma unroll
        for (int off = 8; off < 64; off <<= 1) m = fmaxf(m, __shfl_xor(m, off));

        for (int c = s0; c < s1; c += 8) {
            int e = c + eidx;
            int s = 0;
            float ex = 0.f;
            if (e < s1) {
                s = csr[e];
                ex = __expf(lrelu(el[s * 8 + h] + erh) - m);
            }
            den += ex;
            if (h == 0) s_src[w][eidx] = s;
            s_ex[w][lane] = ex;
            fma_chunk(min(8, s1 - c));
        }
    }
    #pragma unroll
    for (int off = 8; off < 64; off <<= 1) den += __shfl_xor(den, off);
    if (eidx == 0) s_den[w][h] = den;
    float d = fmaxf(s_den[w][hh], 1e-9f);

    ushort4 vh0, vl0, vh1, vl1;
    #pragma unroll
    for (int q = 0; q < 8; ++q) {
        float o = (deg > 0) ? a[q] / d : 0.f;
        o = o > 0.f ? o : (__expf(o) - 1.f);  // ELU (both branches' layer 1)
        unsigned short sh, sl;
        split_bf(o, sh, sl);
        if (q < 4) { ((unsigned short*)&vh0)[q] = sh; ((unsigned short*)&vl0)[q] = sl; }
        else       { ((unsigned short*)&vh1)[q - 4] = sh; ((unsigned short*)&vl1)[q - 4] = sl; }
    }
    int ch = lane << 3;
    unsigned short* dhi = (ch < 256) ? o0hi : o1hi;
    unsigned short* dlo = (ch < 256) ? o0lo : o1lo;
    size_t base = (size_t)i * 256 + (ch & 255);
    *(ushort4*)&dhi[base] = vh0;
    *(ushort4*)&dhi[base + 4] = vh1;
    *(ushort4*)&dlo[base] = vl0;
    *(ushort4*)&dlo[base + 4] = vl1;
}

// ---------------- H=1 aggregation (LDS chunk staging, per R8) --------------

template <int D, int ACT, int SPLITOUT>
__global__ __launch_bounds__(256) void k_agg1(const int* __restrict__ rowptr,
                                              const int* __restrict__ csr,
                                              const float* __restrict__ el,
                                              const float* __restrict__ er,
                                              const _Float16* __restrict__ feat,
                                              unsigned short* __restrict__ ohi,
                                              unsigned short* __restrict__ olo,
                                              float* __restrict__ ofp, int n) {
    __shared__ int   s_src[4][64];
    __shared__ float s_ex[4][64];
    int w = threadIdx.x >> 6;
    int i = blockIdx.x * 4 + w;
    int lane = threadIdx.x & 63;
    if (i >= n) return;
    int s0 = rowptr[i], s1 = rowptr[i + 1];
    int deg = s1 - s0;
    float eri = er[i];
    bool act = lane < D;

    float den = 0.f, acc = 0.f;

    if (deg <= 64) {
        int e = s0 + lane;
        int s = 0;
        float v = -INFINITY;
        if (e < s1) {
            s = csr[e];
            v = lrelu(el[s] + eri);
        }
        float m = v;
        #pragma unroll
        for (int off = 32; off; off >>= 1) m = fmaxf(m, __shfl_xor(m, off));
        float ex = (e < s1) ? __expf(v - m) : 0.f;
        den = ex;
        s_src[w][lane] = s;
        s_ex[w][lane] = ex;
        int j = 0;
        for (; j + 4 <= deg; j += 4) {
            int4   sj = *(const int4*)&s_src[w][j];
            float4 xj = *(const float4*)&s_ex[w][j];
            float f0 = act ? (float)feat[(size_t)sj.x * D + lane] : 0.f;
            float f1 = act ? (float)feat[(size_t)sj.y * D + lane] : 0.f;
            float f2 = act ? (float)feat[(size_t)sj.z * D + lane] : 0.f;
            float f3 = act ? (float)feat[(size_t)sj.w * D + lane] : 0.f;
            acc = fmaf(xj.x, f0, fmaf(xj.y, f1, fmaf(xj.z, f2, fmaf(xj.w, f3, acc))));
        }
        for (; j < deg; ++j)
            acc = fmaf(s_ex[w][j], act ? (float)feat[(size_t)s_src[w][j] * D + lane] : 0.f, acc);
    } else {
        float m = -INFINITY;
        for (int e = s0 + lane; e < s1; e += 64)
            m = fmaxf(m, lrelu(el[csr[e]] + eri));
        #pragma unroll
        for (int off = 32; off; off >>= 1) m = fmaxf(m, __shfl_xor(m, off));

        for (int c = s0; c < s1; c += 64) {
            int e = c + lane;
            int s = 0;
            float ex = 0.f;
            if (e < s1) {
                s = csr[e];
                ex = __expf(lrelu(el[s] + eri) - m);
            }
            den += ex;
            s_src[w][lane] = s;
            s_ex[w][lane] = ex;
            int cnt = min(64, s1 - c);
            int j = 0;
            for (; j + 4 <= cnt; j += 4) {
                int4   sj = *(const int4*)&s_src[w][j];
                float4 xj = *(const float4*)&s_ex[w][j];
                float f0 = act ? (float)feat[(size_t)sj.x * D + lane] : 0.f;
                float f1 = act ? (float)feat[(size_t)sj.y * D + lane] : 0.f;
                float f2 = act ? (float)feat[(size_t)sj.z * D + lane] : 0.f;
                float f3 = act ? (float)feat[(size_t)sj.w * D + lane] : 0.f;
                acc = fmaf(xj.x, f0, fmaf(xj.y, f1, fmaf(xj.z, f2, fmaf(xj.w, f3, acc))));
            }
            for (; j < cnt; ++j)
                acc = fmaf(s_ex[w][j], act ? (float)feat[(size_t)s_src[w][j] * D + lane] : 0.f, acc);
        }
    }
    #pragma unroll
    for (int off = 32; off; off >>= 1) den += __shfl_xor(den, off);

    float o = (s1 > s0) ? acc / fmaxf(den, 1e-9f) : 0.f;
    if (ACT == 1) o = o > 0.f ? o : (__expf(o) - 1.f);
    if (act) {
        if (SPLITOUT) {
            unsigned short hh, ll;
            split_bf(o, hh, ll);
            ohi[(size_t)i * D + lane] = hh;
            olo[(size_t)i * D + lane] = ll;
        } else {
            ofp[(size_t)i * D + lane] = o;
        }
    }
}

// ---------------- launch ----------------

extern "C" void kernel_launch(void* const* d_in, const int* in_sizes, int n_in,
                              void* d_out, int out_size, void* d_ws, size_t ws_size,
                              hipStream_t stream) {
    const float* x    = (const float*)d_in[0];
    const int*   src  = (const int*)d_in[1];
    const int*   dst  = (const int*)d_in[2];
    const float* W00  = (const float*)d_in[3];
    const float* a00l = (const float*)d_in[4];
    const float* a00r = (const float*)d_in[5];
    const float* W01  = (const float*)d_in[6];
    const float* a01l = (const float*)d_in[7];
    const float* a01r = (const float*)d_in[8];
    const float* W0f  = (const float*)d_in[9];
    const float* a0fl = (const float*)d_in[10];
    const float* a0fr = (const float*)d_in[11];
    const float* W10  = (const float*)d_in[12];
    const float* a10l = (const float*)d_in[13];
    const float* a10r = (const float*)d_in[14];
    const float* W1f  = (const float*)d_in[15];
    const float* a1fl = (const float*)d_in[16];
    const float* a1fr = (const float*)d_in[17];
    const float* W1o  = (const float*)d_in[18];
    const float* a1ol = (const float*)d_in[19];
    const float* a1or = (const float*)d_in[20];
    float* out = (float*)d_out;

    const int n = in_sizes[0] / 256;  // 50000
    const int e = in_sizes[1];        // 800000
    const int C = 40;

    char* p = (char*)d_ws;
    auto alloc = [&](size_t bytes) -> void* {
        void* r = (void*)p;
        p += (bytes + 255) & ~(size_t)255;
        return r;
    };
    int*   deg     = (int*)alloc((size_t)n * 4);
    int*   tmp     = (int*)alloc((size_t)n * 4);
    int*   bsum    = (int*)alloc(64 * 4);
    int*   rowptr  = (int*)alloc((size_t)(n + 1) * 4);
    int*   cursor  = (int*)alloc((size_t)n * 4);
    int*   csr     = (int*)alloc((size_t)e * 4);
    float* el      = (float*)alloc((size_t)n * 8 * 4);
    float* er      = (float*)alloc((size_t)n * 8 * 4);
    _Float16* feat01 = (_Float16*)alloc((size_t)n * 512 * 2);   // layer1 fused out; reused later
    unsigned short* xhi = (unsigned short*)alloc((size_t)n * 256 * 2);
    unsigned short* xlo = (unsigned short*)alloc((size_t)n * 256 * 2);
    unsigned short* h0hi = (unsigned short*)alloc((size_t)n * 256 * 2);
    unsigned short* h0lo = (unsigned short*)alloc((size_t)n * 256 * 2);
    // branch1 h buffers alias xhi/xlo: x is dead after the fused layer-1 GEMM,
    // and k_agg8 (which writes these) runs strictly after it on the stream.
    unsigned short* h1hi = xhi;
    unsigned short* h1lo = xlo;
    unsigned short* Bt1h = (unsigned short*)alloc(512 * 256 * 2);  // [W00t; W10t]
    unsigned short* Bt1l = (unsigned short*)alloc(512 * 256 * 2);
    unsigned short* W01h = (unsigned short*)alloc(256 * 64 * 2);
    unsigned short* W01l = (unsigned short*)alloc(256 * 64 * 2);
    unsigned short* W0fh = (unsigned short*)alloc(64 * 40 * 2);
    unsigned short* W0fl = (unsigned short*)alloc(64 * 40 * 2);
    unsigned short* W1fh = (unsigned short*)alloc(256 * 64 * 2);
    unsigned short* W1fl = (unsigned short*)alloc(256 * 64 * 2);
    unsigned short* W1oh = (unsigned short*)alloc(64 * 40 * 2);
    unsigned short* W1ol = (unsigned short*)alloc(64 * 40 * 2);

    // ---- CSR build ----
    hipMemsetAsync(deg, 0, (size_t)n * 4, stream);
    k_hist<<<(e + 255) / 256, 256, 0, stream>>>(dst, deg, e);
    int nb = (n + 1023) / 1024;
    k_scan1<<<nb, 1024, 0, stream>>>(deg, tmp, bsum, n);
    k_scan2<<<1, 1, 0, stream>>>(bsum, nb);
    k_scan3<<<(n + 255) / 256, 256, 0, stream>>>(deg, tmp, bsum, rowptr, cursor, n);
    k_scatter<<<(e + 255) / 256, 256, 0, stream>>>(src, dst, cursor, csr, e);

    // ---- casts ----
    int nel = n * 256;
    k_castx<<<(nel + 255) / 256, 256, 0, stream>>>(x, xhi, xlo, nel);
    k_castw<<<(256 * 256 + 255) / 256, 256, 0, stream>>>(W00, Bt1h, Bt1l, 256, 256);
    k_castw<<<(256 * 256 + 255) / 256, 256, 0, stream>>>(W10, Bt1h + 256 * 256, Bt1l + 256 * 256, 256, 256);
    k_castw<<<(256 * 64 + 255) / 256, 256, 0, stream>>>(W01, W01h, W01l, 256, 64);
    k_castw<<<(64 * 40 + 255) / 256, 256, 0, stream>>>(W0f, W0fh, W0fl, 64, 40);
    k_castw<<<(256 * 64 + 255) / 256, 256, 0, stream>>>(W1f, W1fh, W1fl, 256, 64);
    k_castw<<<(64 * 40 + 255) / 256, 256, 0, stream>>>(W1o, W1oh, W1ol, 64, 40);

    int gw1 = (n + 3) / 4;
    int gw8 = (n * 8 + 3) / 4;
    _Float16* feat = feat01;  // reused for all later (smaller) layers

    // ---- fused layer 1 (both branches) ----
    gemm_split(xhi, xlo, Bt1h, Bt1l, feat01, n, 512, 256, stream);
    k_attn8<<<gw8, 256, 0, stream>>>(feat01, a00l, a00r, a10l, a10r, el, er, n);
    k_agg8<<<gw1, 256, 0, stream>>>(rowptr, csr, el, er, feat01, h0hi, h0lo, h1hi, h1lo, n);

    // ---- branch 0 tail ----
    gemm_split(h0hi, h0lo, W01h, W01l, feat, n, 64, 256, stream);
    k_attn<1, 64><<<gw1, 256, 0, stream>>>(feat, a01l, a01r, el, er, n);
    k_agg1<64, 1, 1><<<gw1, 256, 0, stream>>>(rowptr, csr, el, er, feat, h0hi, h0lo, nullptr, n);

    gemm_split(h0hi, h0lo, W0fh, W0fl, feat, n, C, 64, stream);
    k_attn<1, 40><<<gw1, 256, 0, stream>>>(feat, a0fl, a0fr, el, er, n);
    k_agg1<40, 0, 0><<<gw1, 256, 0, stream>>>(rowptr, csr, el, er, feat, nullptr, nullptr, out, n);

    // ---- branch 1 tail ----
    gemm_split(h1hi, h1lo, W1fh, W1fl, feat, n, 64, 256, stream);
    k_attn<1, 64><<<gw1, 256, 0, stream>>>(feat, a1fl, a1fr, el, er, n);
    k_agg1<64, 0, 1><<<gw1, 256, 0, stream>>>(rowptr, csr, el, er, feat, h1hi, h1lo, nullptr, n);

    gemm_split(h1hi, h1lo, W1oh, W1ol, feat, n, C, 64, stream);
    k_attn<1, 40><<<gw1, 256, 0, stream>>>(feat, a1ol, a1or, el, er, n);
    k_agg1<40, 1, 0><<<gw1, 256, 0, stream>>>(rowptr, csr, el, er, feat, nullptr, nullptr,
                                              out + (size_t)n * C, n);
}